// Round 13
// baseline (198.506 us; speedup 1.0000x reference)
//
#include <hip/hip_runtime.h>
#include <hip/hip_bf16.h>

// SelfAttention: x[2,2048,1024] fp32; w_qkv[3072,1024]; w_out[1024,1024]; b_out[1024]
// Pipeline:
//  (0) cvt_all: x, w_qkv (q rows pre-scaled by 0.125*log2e), w_out -> bf16 ws
//  (1) gemm128<0,128>: qkv = x @ w_qkv^T. q,k -> qk_ws bf16 [4096,2048];
//      v -> vt_ws transposed [b][h][d][key]
//  (2) attn_kernel<PARTIAL> (r7/r11 per-wave pipeline — best measured):
//      32x32x16 MFMA, 2x2 wave grid, pitch-72 LDS (conflict-free), register
//      prefetch, 2 barriers/chunk, 256-thread blocks (narrow barriers).
//      PARTIAL=1: key range split in 2 (blockIdx.z), 2048 blocks = 8/CU =
//      32 waves/CU (vs 16); unnormalized fp32 O/l partials -> ws; then
//      attn_combine sums partials, normalizes, emits bf16.
//      PARTIAL=0 fallback (ws too small): exact r11, 1024 blocks.
//  (3) gemm128<1,64>: out = attn @ w_out^T + b_out
// GEMM: BM=128, BK=64, global_load_lds w=16, XOR-swizzle (2-way banks, free).
// 32x32 C/D layout: col=lane&31 (B's n), row=(reg&3)+8*(reg>>2)+4*(lane>>5).
// 32x32 A/B frag: lane&31 = m/n, k = (lane>>5)*8 + j (8 contiguous bf16 = 16 B).
// NOTE (journal): r8 LDS-dbuf, r9 LDS-free, r10 gl2lds-dbuf, r12 512-thr-block
// attn variants all regressed vs r7/r11 (67.5 / 134 / 68.6 / 66.9 vs 61 us).
// gl2lds forces pitch-128B tiles -> 4-way bank conflicts; wide blocks ->
// barrier convoys. Occupancy must come from MORE BLOCKS, not wider blocks.

#define SEQ   2048
#define BATCH 2
#define CDIM  1024
#define NH    16
#define HD    64
#define NTOK  (BATCH*SEQ)
#define QSCALE 0.18033688011f   // 0.125 * log2(e)

typedef __attribute__((ext_vector_type(8)))  short s16x8;
typedef __attribute__((ext_vector_type(4)))  float f32x4;
typedef __attribute__((ext_vector_type(16))) float f32x16;
typedef __attribute__((ext_vector_type(4)))  unsigned u32x4;
typedef __attribute__((ext_vector_type(2)))  __bf16 bf16x2;

__device__ __forceinline__ short f2bf(float x) {
  unsigned u = __builtin_bit_cast(unsigned, x);
  u = (u + 0x7fffu + ((u >> 16) & 1u)) >> 16;
  return (short)u;
}

// pack two fp32 -> bf16x2 in one u32 (low=a, high=b)
__device__ __forceinline__ unsigned f2bf2(float a, float b) {
#if __has_builtin(__builtin_amdgcn_cvt_pk_bf16_f32)
  bf16x2 v = __builtin_amdgcn_cvt_pk_bf16_f32(a, b);
  return __builtin_bit_cast(unsigned, v);
#else
  unsigned ua = __builtin_bit_cast(unsigned, a) + 0x8000u;
  unsigned ub = __builtin_bit_cast(unsigned, b) + 0x8000u;
  return (ub & 0xffff0000u) | (ua >> 16);
#endif
}

__device__ __forceinline__ float exp2_fast(float x) {
  return __builtin_amdgcn_exp2f(x);   // v_exp_f32
}

__device__ __forceinline__ void gl2lds16(const short* g, short* l) {
  __builtin_amdgcn_global_load_lds(
      (const __attribute__((address_space(1))) void*)g,
      (__attribute__((address_space(3))) void*)l, 16, 0, 0);
}

// ---------------------------------------------------------------------------
// Fused fp32 -> bf16 converts (x | w_qkv(q-scaled) | w_out), 2048 elem/block.
// ---------------------------------------------------------------------------
__global__ __launch_bounds__(256) void cvt_all(
    const float* __restrict__ x, const float* __restrict__ wqkv,
    const float* __restrict__ wout, short* __restrict__ x_bf,
    short* __restrict__ wqkv_bf, short* __restrict__ wout_bf)
{
  int blk = blockIdx.x;
  const float* src; short* dst; int base; float scale = 1.0f;
  if (blk < 2048)      { src = x;    dst = x_bf;    base = blk; }
  else if (blk < 3584) { src = wqkv; dst = wqkv_bf; base = blk - 2048;
                         if (base < 512) scale = QSCALE; }  // q rows
  else                 { src = wout; dst = wout_bf; base = blk - 3584; }
  size_t i = ((size_t)base * 256 + threadIdx.x) * 8;
  float4 v0 = *(const float4*)(src + i);
  float4 v1 = *(const float4*)(src + i + 4);
  s16x8 p;
  p[0]=f2bf(v0.x*scale); p[1]=f2bf(v0.y*scale); p[2]=f2bf(v0.z*scale); p[3]=f2bf(v0.w*scale);
  p[4]=f2bf(v1.x*scale); p[5]=f2bf(v1.y*scale); p[6]=f2bf(v1.z*scale); p[7]=f2bf(v1.w*scale);
  *(s16x8*)(dst + i) = p;
}

// ---------------------------------------------------------------------------
// GEMM: C[M,N] = A[M,K] @ B[N,K]^T, bf16. BM=128, BK=64, 4 waves, 256 thr.
// BN=128: wave 64x64 acc[4][4]; BN=64: wave 64x32 acc[4][2].
// LDS [rows][64] shorts; 16B chunk at (row,pos) holds global chunk
// pos ^ (row&7); frag reads hit bank-group quad^(lrow&7) -> 2-way (free).
// MODE 0: QKV epilogue (q,k -> qk bf16 pitch 2048; v -> vt transposed).
// MODE 1: fp32 + bias epilogue.
// ---------------------------------------------------------------------------
template<int MODE, int BN>
__global__ __launch_bounds__(256) void gemm128(
    const short* __restrict__ A, const short* __restrict__ B,
    const float* __restrict__ bias, void* __restrict__ Cp,
    short* __restrict__ vt, int M, int N, int K)
{
  constexpr int TN = BN / 32;     // acc tiles per wave in N (4 or 2)
  constexpr int NB = BN / 32;     // B-staging gl2lds per thread (4 or 2)

  __shared__ __align__(16) short As[128 * 64];
  __shared__ __align__(16) short Bs[BN * 64];

  const int t    = threadIdx.x;
  const int w    = t >> 6, lane = t & 63;
  const int bm   = blockIdx.y * 128, bn = blockIdx.x * BN;
  const int wm   = (w >> 1) * 64, wn = (w & 1) * (BN / 2);
  const int lrow = lane & 15, quad = lane >> 4;

  int goffA[4], goffB[NB];
#pragma unroll
  for (int i = 0; i < 4; i++) {
    int L   = (w * 4 + i) * 64 + lane;     // 16B-chunk index in 128x64 tile
    int row = L >> 3, pos = L & 7;
    int src = pos ^ (row & 7);
    goffA[i] = (bm + row) * K + src * 8;
  }
#pragma unroll
  for (int i = 0; i < NB; i++) {
    int L   = (w * NB + i) * 64 + lane;
    int row = L >> 3, pos = L & 7;
    int src = pos ^ (row & 7);
    goffB[i] = (bn + row) * K + src * 8;
  }
  const int fk0 = (quad ^ (lrow & 7)) * 8;
  const int fk1 = fk0 ^ 32;

  f32x4 acc[4][TN];
#pragma unroll
  for (int i = 0; i < 4; i++)
#pragma unroll
    for (int j = 0; j < TN; j++) acc[i][j] = (f32x4){0.f, 0.f, 0.f, 0.f};

  for (int k0 = 0; k0 < K; k0 += 64) {
    __syncthreads();
#pragma unroll
    for (int i = 0; i < 4; i++)
      gl2lds16(A + goffA[i] + k0, &As[(w * 4 + i) * 512]);
#pragma unroll
    for (int i = 0; i < NB; i++)
      gl2lds16(B + goffB[i] + k0, &Bs[(w * NB + i) * 512]);
    __syncthreads();

    s16x8 a[4][2], b[TN][2];
#pragma unroll
    for (int tm = 0; tm < 4; tm++) {
      a[tm][0] = *(const s16x8*)&As[(wm + tm * 16 + lrow) * 64 + fk0];
      a[tm][1] = *(const s16x8*)&As[(wm + tm * 16 + lrow) * 64 + fk1];
    }
#pragma unroll
    for (int tn = 0; tn < TN; tn++) {
      b[tn][0] = *(const s16x8*)&Bs[(wn + tn * 16 + lrow) * 64 + fk0];
      b[tn][1] = *(const s16x8*)&Bs[(wn + tn * 16 + lrow) * 64 + fk1];
    }
#pragma unroll
    for (int hh = 0; hh < 2; hh++)
#pragma unroll
      for (int tm = 0; tm < 4; tm++)
#pragma unroll
        for (int tn = 0; tn < TN; tn++)
          acc[tm][tn] = __builtin_amdgcn_mfma_f32_16x16x32_bf16(
              a[tm][hh], b[tn][hh], acc[tm][tn], 0, 0, 0);
  }

  if (MODE == 1) {
#pragma unroll
    for (int tm = 0; tm < 4; tm++)
#pragma unroll
      for (int tn = 0; tn < TN; tn++)
#pragma unroll
        for (int i = 0; i < 4; i++) {
          int row = bm + wm + tm * 16 + quad * 4 + i;
          int col = bn + wn + tn * 16 + lrow;
          ((float*)Cp)[(size_t)row * N + col] = acc[tm][tn][i] + bias[col];
        }
  } else if (bn < 2 * CDIM) {
#pragma unroll
    for (int tm = 0; tm < 4; tm++)
#pragma unroll
      for (int tn = 0; tn < TN; tn++)
#pragma unroll
        for (int i = 0; i < 4; i++) {
          int row = bm + wm + tm * 16 + quad * 4 + i;
          int col = bn + wn + tn * 16 + lrow;
          ((short*)Cp)[(size_t)row * 2048 + col] = f2bf(acc[tm][tn][i]);
        }
  } else {
#pragma unroll
    for (int tm = 0; tm < 4; tm++)
#pragma unroll
      for (int tn = 0; tn < TN; tn++) {
        int vcol = bn - 2 * CDIM + wn + tn * 16 + lrow;
        int h    = vcol >> 6, d = vcol & 63;
        int r0   = bm + wm + tm * 16 + quad * 4;
        int bb   = r0 >> 11, key = r0 & (SEQ - 1);
        size_t off = (((size_t)(bb * NH + h) * HD + d) << 11) + key;
        uint2 pk;
        pk.x = f2bf2(acc[tm][tn][0], acc[tm][tn][1]);
        pk.y = f2bf2(acc[tm][tn][2], acc[tm][tn][3]);
        *(uint2*)(vt + off) = pk;
      }
  }
}

// ---------------------------------------------------------------------------
// Flash attention (r7/r11 structure). 32x32x16 MFMA, 2x2 wave grid (wq=q-half,
// wk=key-half). Register prefetch, single pitch-72 LDS buffer (conflict-free),
// 2 barriers/chunk, 256-thread blocks. S^T = mfma(K, Q(regs)); C->A via
// shfl_xor(32) in regs; no-max softmax (exp2, scale pre-folded).
// PARTIAL=0: 32 chunks, final bf16 output (exact r11).
// PARTIAL=1: blockIdx.z = ks selects half the key range (16 chunks);
//            epilogue writes unnormalized fp32 O and l partials to Op/Lp.
// ---------------------------------------------------------------------------
template<int PARTIAL>
__global__ __launch_bounds__(256) void attn_kernel(
    const short* __restrict__ qk, const short* __restrict__ vt,
    short* __restrict__ attn_out, float* __restrict__ Op,
    float* __restrict__ Lp)
{
  __shared__ __align__(16) short smem[2 * 64 * 72];   // Ks | Vs, 18 KB
  short* Ks = smem;
  short* Vs = smem + 64 * 72;

  const int t   = threadIdx.x;
  const int w   = t >> 6, lane = t & 63;
  const int l31 = lane & 31, h = lane >> 5;
  const int wq  = w & 1, wk = w >> 1;
  const int bh  = blockIdx.x;
  const int b   = bh >> 4, hd = bh & (NH - 1);
  const int q0  = blockIdx.y * 64;
  const int ks  = PARTIAL ? blockIdx.z : 0;
  const int n0base = ks * (SEQ / 2);
  const int NCH = PARTIAL ? SEQ / 128 : SEQ / 64;

  float* Opk = PARTIAL ? Op + (size_t)ks * NTOK * CDIM : nullptr;
  float* Lpk = PARTIAL ? Lp + (size_t)ks * BATCH * NH * SEQ : nullptr;

  const short* base  = qk + (size_t)(b * SEQ) * 2048 + hd * HD;
  const short* vbase = vt + ((size_t)(b * NH + hd) * HD) * SEQ;

  // Q B-frags in registers (pre-scaled): n=q, k=d=c*16+h*8+j
  s16x8 qf[4];
  {
    const short* qp = base + (size_t)(q0 + wq * 32 + l31) * 2048;
#pragma unroll
    for (int c = 0; c < 4; c++) qf[c] = *(const s16x8*)(qp + c * 16 + h * 8);
  }

  f32x16 o0 = {}, o1 = {};
  float lsum = 0.f;

  const int kr = t >> 2, kc = (t & 3) * 16;   // staging: 64 rows x 64, 16/thr

  // prefetch chunk 0 into registers
  s16x8 pk0, pk1, pv0, pv1;
  {
    const short* kp = base + (size_t)(n0base + kr) * 2048 + CDIM + kc;
    pk0 = *(const s16x8*)kp; pk1 = *(const s16x8*)(kp + 8);
    const short* vp = vbase + (size_t)kr * SEQ + n0base + kc;
    pv0 = *(const s16x8*)vp; pv1 = *(const s16x8*)(vp + 8);
  }

  for (int c = 0; c < NCH; c++) {
    const int n0 = n0base + c * 64;
    __syncthreads();                          // prior chunk's frag reads done
    *(s16x8*)&Ks[kr * 72 + kc]     = pk0;
    *(s16x8*)&Ks[kr * 72 + kc + 8] = pk1;
    *(s16x8*)&Vs[kr * 72 + kc]     = pv0;
    *(s16x8*)&Vs[kr * 72 + kc + 8] = pv1;
    __syncthreads();                          // tiles ready

    // issue next chunk's loads (overlap with compute below)
    {
      int nn = (c + 1 < NCH) ? n0 + 64 : n0;
      const short* kp = base + (size_t)(nn + kr) * 2048 + CDIM + kc;
      pk0 = *(const s16x8*)kp; pk1 = *(const s16x8*)(kp + 8);
      const short* vp = vbase + (size_t)kr * SEQ + nn + kc;
      pv0 = *(const s16x8*)vp; pv1 = *(const s16x8*)(vp + 8);
    }

    // S^T[key][q]: A = K rows (wk half), B = Q regs
    f32x16 s = {};
#pragma unroll
    for (int cc = 0; cc < 4; cc++) {
      s16x8 kf = *(const s16x8*)&Ks[(wk * 32 + l31) * 72 + cc * 16 + h * 8];
      s = __builtin_amdgcn_mfma_f32_32x32x16_bf16(kf, qf[cc], s, 0, 0, 0);
    }

    // softmax + pack: reg r -> key (r&3)+8*(r>>2)+4h (local to wave's half)
    uint2 pg[4];
#pragma unroll
    for (int g = 0; g < 4; g++) {
      float p0 = exp2_fast(s[4 * g + 0]);
      float p1 = exp2_fast(s[4 * g + 1]);
      float p2 = exp2_fast(s[4 * g + 2]);
      float p3 = exp2_fast(s[4 * g + 3]);
      lsum += (p0 + p1) + (p2 + p3);
      pg[g].x = f2bf2(p0, p1);
      pg[g].y = f2bf2(p2, p3);
    }

    // C->A: per 16-key chunk kc2, swap 4-key groups between lane<->lane+32
    s16x8 pf[2];
#pragma unroll
    for (int kc2 = 0; kc2 < 2; kc2++) {
      uint2 send = h ? pg[2 * kc2] : pg[2 * kc2 + 1];
      uint2 recv;
      recv.x = (unsigned)__shfl_xor((int)send.x, 32);
      recv.y = (unsigned)__shfl_xor((int)send.y, 32);
      uint2 lo = h ? recv : pg[2 * kc2];
      uint2 hi = h ? pg[2 * kc2 + 1] : recv;
      u32x4 f = {lo.x, lo.y, hi.x, hi.y};
      pf[kc2] = __builtin_bit_cast(s16x8, f);
    }

    // PV: O[q][d] += P * V over wave's 32 keys; B-frag from Vs[d][key]
#pragma unroll
    for (int kc2 = 0; kc2 < 2; kc2++) {
      s16x8 v0 = *(const s16x8*)&Vs[l31 * 72        + wk * 32 + kc2 * 16 + h * 8];
      s16x8 v1 = *(const s16x8*)&Vs[(32 + l31) * 72 + wk * 32 + kc2 * 16 + h * 8];
      o0 = __builtin_amdgcn_mfma_f32_32x32x16_bf16(pf[kc2], v0, o0, 0, 0, 0);
      o1 = __builtin_amdgcn_mfma_f32_32x32x16_bf16(pf[kc2], v1, o1, 0, 0, 0);
    }
  }

  // ---- epilogue: cross-wk reduction of O and l, then store ----
  lsum += __shfl_xor(lsum, 32);          // combine h halves (disjoint keys)

  float* Ored = (float*)smem;            // [2 wq][32 q][64 d] = 16 KB
  float* Lred = (float*)smem + 4096;     // [64]

  __syncthreads();                       // drain last chunk's LDS reads
  if (wk == 0) {
#pragma unroll
    for (int r = 0; r < 16; r++) {
      int ql = (r & 3) + 8 * (r >> 2) + 4 * h;
      Ored[(wq * 32 + ql) * 64 + l31]      = o0[r];
      Ored[(wq * 32 + ql) * 64 + 32 + l31] = o1[r];
    }
    if (lane < 32) Lred[wq * 32 + l31] = lsum;
  }
  __syncthreads();
  if (wk == 1 && lane < 32) Lred[wq * 32 + l31] += lsum;
  __syncthreads();
  if (wk == 1) {
#pragma unroll
    for (int r = 0; r < 16; r++) {
      int ql = (r & 3) + 8 * (r >> 2) + 4 * h;
      float lq = Lred[wq * 32 + ql];
      int qg = q0 + wq * 32 + ql;
      size_t rowb = (size_t)(b * SEQ + qg) * CDIM + hd * HD;
      float v0 = o0[r] + Ored[(wq * 32 + ql) * 64 + l31];
      float v1 = o1[r] + Ored[(wq * 32 + ql) * 64 + 32 + l31];
      if (PARTIAL) {
        Opk[rowb + l31]      = v0;
        Opk[rowb + 32 + l31] = v1;
        if (l31 == 0) Lpk[(size_t)(b * NH + hd) * SEQ + qg] = lq;
      } else {
        float inv = 1.0f / lq;
        attn_out[rowb + l31]      = f2bf(v0 * inv);
        attn_out[rowb + 32 + l31] = f2bf(v1 * inv);
      }
    }
  }
}

// ---------------------------------------------------------------------------
// Combine the 2 key-split partials: attn = (Op0+Op1) / (l0+l1), bf16 out.
// 8 elems/thread; 8 cols share one head (col base multiple of 8 < 64-split).
// ---------------------------------------------------------------------------
__global__ __launch_bounds__(256) void attn_combine(
    const float* __restrict__ Op, const float* __restrict__ Lp,
    short* __restrict__ attn_out)
{
  size_t i = ((size_t)blockIdx.x * 256 + threadIdx.x) * 8;
  int row = (int)(i >> 10);            // / CDIM
  int col = (int)(i & (CDIM - 1));
  int b = row >> 11, q = row & (SEQ - 1), hd = col >> 6;
  size_t lidx = (size_t)(b * NH + hd) * SEQ + q;
  float l = Lp[lidx] + Lp[lidx + (size_t)BATCH * NH * SEQ];
  float inv = 1.0f / l;
  const float* p0 = Op + i;
  const float* p1 = Op + i + (size_t)NTOK * CDIM;
  float4 a0 = *(const float4*)p0, a1 = *(const float4*)(p0 + 4);
  float4 c0 = *(const float4*)p1, c1 = *(const float4*)(p1 + 4);
  s16x8 o;
  o[0] = f2bf((a0.x + c0.x) * inv);
  o[1] = f2bf((a0.y + c0.y) * inv);
  o[2] = f2bf((a0.z + c0.z) * inv);
  o[3] = f2bf((a0.w + c0.w) * inv);
  o[4] = f2bf((a1.x + c1.x) * inv);
  o[5] = f2bf((a1.y + c1.y) * inv);
  o[6] = f2bf((a1.z + c1.z) * inv);
  o[7] = f2bf((a1.w + c1.w) * inv);
  *(s16x8*)(attn_out + i) = o;
}

// ---------------------------------------------------------------------------
extern "C" void kernel_launch(void* const* d_in, const int* in_sizes, int n_in,
                              void* d_out, int out_size, void* d_ws, size_t ws_size,
                              hipStream_t stream)
{
  const float* x     = (const float*)d_in[0];
  const float* w_qkv = (const float*)d_in[1];
  const float* w_out = (const float*)d_in[2];
  const float* b_out = (const float*)d_in[3];

  short* qk_ws   = (short*)d_ws;                         // 4096*2048 = 16 MB
  short* vt_ws   = qk_ws  + (size_t)NTOK * 2048;         // 4096*1024 =  8 MB
  short* x_bf    = vt_ws  + (size_t)NTOK * CDIM;         // 4096*1024 =  8 MB
  short* attn_ws = x_bf;                                 // alias (x_bf dead)
  short* wqkv_bf = x_bf   + (size_t)NTOK * CDIM;         // 3072*1024 =  6 MB
  short* wout_bf = wqkv_bf + (size_t)3 * CDIM * CDIM;    // 1024*1024 =  2 MB

  // key-split partial buffers (beyond the 40 MB base)
  const size_t base_b = (size_t)40 * 1024 * 1024;
  float* Op = (float*)((char*)d_ws + base_b);            // 2 x 16 MB fp32
  float* Lp = (float*)((char*)d_ws + base_b + (size_t)32 * 1024 * 1024);
  const size_t need = base_b + (size_t)32 * 1024 * 1024
                    + (size_t)2 * BATCH * NH * SEQ * sizeof(float);

  dim3 blk(256);

  cvt_all<<<dim3(4096), blk, 0, stream>>>(x, w_qkv, w_out, x_bf, wqkv_bf, wout_bf);

  gemm128<0, 128><<<dim3(3 * CDIM / 128, NTOK / 128), blk, 0, stream>>>(
      x_bf, wqkv_bf, nullptr, qk_ws, vt_ws, NTOK, 3 * CDIM, CDIM);

  if (ws_size >= need) {
    attn_kernel<1><<<dim3(BATCH * NH, SEQ / 64, 2), blk, 0, stream>>>(
        qk_ws, vt_ws, nullptr, Op, Lp);
    attn_combine<<<dim3(NTOK * CDIM / 2048), blk, 0, stream>>>(Op, Lp, attn_ws);
  } else {
    attn_kernel<0><<<dim3(BATCH * NH, SEQ / 64), blk, 0, stream>>>(
        qk_ws, vt_ws, attn_ws, nullptr, nullptr);
  }

  gemm128<1, 64><<<dim3(CDIM / 64, NTOK / 128), blk, 0, stream>>>(
      attn_ws, wout_bf, b_out, d_out, nullptr, NTOK, CDIM, CDIM);
}